// Round 6
// baseline (17996.761 us; speedup 1.0000x reference)
//
#include <hip/hip_runtime.h>

#define BB 64
#define TT 2048
#define FF 15
#define UU 256
#define N3 768

typedef _Float16 f16;
typedef __attribute__((ext_vector_type(8))) _Float16 f16x8;   // 4 VGPRs
typedef __attribute__((ext_vector_type(4))) float     f32x4;  // 4 VGPRs

__device__ float g_seq1[BB * TT * UU];           // 134 MB
__device__ float g_xp[(size_t)BB * TT * N3];     // 402 MB
__device__ f16x8 g_Up1[48 * 512];                // U1 B-fragments (6 nt x 8 kt x 512)
__device__ f16x8 g_Up2[48 * 512];
__device__ float g_bias1[N3];                    // b_in + (col<512 ? b_rec : 0)
__device__ float g_bias2[N3];

// --- pack U (fp32 [256][768]) into MFMA B-operand fragments -----------------
// Column remap: wave w owns gate-units u in [w*32, w*32+32); its 6 N-tiles are
// (trio 0: z,r,hh for u in [w*32,w*32+16)), (trio 1: same for +16).
// B-frag lane map (16x16x32): n = lane&15, k = (lane>>4)*8 + j.
__global__ __launch_bounds__(256) void prep_upack(const float* __restrict__ U,
                                                  f16x8* __restrict__ Up) {
    int idx = blockIdx.x * 256 + threadIdx.x;    // (nt*8+kt)*512 + w*64 + lane
    int f = idx >> 9, rem = idx & 511;           // f in [0,48)
    int w = rem >> 6, lane = rem & 63;
    int nt = f >> 3, kt = f & 7;
    int q = lane >> 4, c = lane & 15;
    int trio = nt / 3, gate = nt % 3;
    int g = gate * 256 + w * 32 + trio * 16 + c;     // U column
    f16x8 v;
#pragma unroll
    for (int j = 0; j < 8; j++) v[j] = (f16)U[(kt * 32 + q * 8 + j) * N3 + g];
    Up[idx] = v;
}

__global__ __launch_bounds__(256) void prep_bias(const float* __restrict__ b,
                                                 float* __restrict__ bias) {
    int j = blockIdx.x * 256 + threadIdx.x;
    bias[j] = b[j] + (j < 512 ? b[N3 + j] : 0.f);
}

// --- xp1 = x @ W1 + bias   (K=15) -------------------------------------------
__global__ __launch_bounds__(256) void gemm_k15(
    const float* __restrict__ x, const float* __restrict__ W1,
    const float* __restrict__ bin, float* __restrict__ C) {
    __shared__ float xr[8][FF];
    const int m0 = blockIdx.x * 8;
    const int j  = blockIdx.y * 256 + threadIdx.x;
    if (threadIdx.x < 8 * FF) {
        int r = threadIdx.x / FF, k = threadIdx.x - r * FF;
        xr[r][k] = x[(size_t)(m0 + r) * FF + k];
    }
    __syncthreads();
    float wv[FF];
#pragma unroll
    for (int k = 0; k < FF; k++) wv[k] = W1[k * N3 + j];
    const float bj = bin[j];
#pragma unroll
    for (int r = 0; r < 8; r++) {
        float a = bj;
#pragma unroll
        for (int k = 0; k < FF; k++) a += xr[r][k] * wv[k];
        C[(size_t)(m0 + r) * N3 + j] = a;
    }
}

// --- xp2 = seq1 @ W2 + bias  (M=131072, N=768, K=256), padded LDS -----------
__global__ __launch_bounds__(256) void gemm_xp(
    const float* __restrict__ A, const float* __restrict__ Bw,
    const float* __restrict__ bin, float* __restrict__ C) {
    __shared__ float As[16][68];     // +4 pad: kills 4-way write conflicts
    __shared__ float Bs[16][68];
    const int tid = threadIdx.x;
    const int m0 = blockIdx.x * 64, n0 = blockIdx.y * 64;
    const int tm = (tid & 15) * 4;
    const int tn = (tid >> 4) * 4;
    float acc[4][4] = {};
    const int lm = tid >> 2, lk = (tid & 3) * 4;
    const int lkb = tid >> 4, ln = (tid & 15) * 4;
    for (int k0 = 0; k0 < 256; k0 += 16) {
        float4 av = *(const float4*)&A[(size_t)(m0 + lm) * 256 + k0 + lk];
        float4 bv = *(const float4*)&Bw[(size_t)(k0 + lkb) * N3 + n0 + ln];
        As[lk + 0][lm] = av.x; As[lk + 1][lm] = av.y;
        As[lk + 2][lm] = av.z; As[lk + 3][lm] = av.w;
        *(float4*)&Bs[lkb][ln] = bv;
        __syncthreads();
#pragma unroll
        for (int kk = 0; kk < 16; kk++) {
            float4 a = *(const float4*)&As[kk][tm];
            float4 b = *(const float4*)&Bs[kk][tn];
            acc[0][0] += a.x * b.x; acc[0][1] += a.x * b.y; acc[0][2] += a.x * b.z; acc[0][3] += a.x * b.w;
            acc[1][0] += a.y * b.x; acc[1][1] += a.y * b.y; acc[1][2] += a.y * b.z; acc[1][3] += a.y * b.w;
            acc[2][0] += a.z * b.x; acc[2][1] += a.z * b.y; acc[2][2] += a.z * b.z; acc[2][3] += a.z * b.w;
            acc[3][0] += a.w * b.x; acc[3][1] += a.w * b.y; acc[3][2] += a.w * b.z; acc[3][3] += a.w * b.w;
        }
        __syncthreads();
    }
#pragma unroll
    for (int i = 0; i < 4; i++) {
        float4 o = make_float4(acc[i][0] + bin[n0 + tn + 0], acc[i][1] + bin[n0 + tn + 1],
                               acc[i][2] + bin[n0 + tn + 2], acc[i][3] + bin[n0 + tn + 3]);
        *(float4*)&C[(size_t)(m0 + tm + i) * N3 + n0 + tn] = o;
    }
}

// --- GRU recurrence via MFMA. 4 WGs x 512 threads; WG owns 16 batch rows. ---
// Per step: C(16x768) = H(16x256) @ U(256x768) with mfma_f32_16x16x32_f16.
// U resident in registers (48 frags, pinned). h double-buffered in LDS
// (A-layout). Gate trios co-located per wave -> gate combine fully in-lane.
__global__ __launch_bounds__(512, 2) void gru_mfma(
    const f16x8* __restrict__ Up, const float* __restrict__ brec,
    const float* __restrict__ xp, float* __restrict__ seq_out,
    float* __restrict__ state_out, float* __restrict__ extra_out) {
    const int tid = threadIdx.x;
    const int w = tid >> 6, lane = tid & 63, q = lane >> 4, c = lane & 15;
    const int m0 = blockIdx.x * 16;

    __shared__ __align__(16) f16 hbuf[2][16][264];   // A-layout h, +8 pad

    // U fragments -> registers, pinned against remat/sink
    f16x8 uf[6][8];
#pragma unroll
    for (int nt = 0; nt < 6; nt++)
#pragma unroll
        for (int kt = 0; kt < 8; kt++) {
            uf[nt][kt] = Up[(nt * 8 + kt) * 512 + w * 64 + lane];
            asm volatile("" : "+v"(uf[nt][kt]));
        }

    float br3[2];
#pragma unroll
    for (int i = 0; i < 2; i++) br3[i] = brec[512 + w * 32 + i * 16 + c];

    float h_old[2][4] = {{0.f, 0.f, 0.f, 0.f}, {0.f, 0.f, 0.f, 0.f}};

    for (int idx = tid; idx < 4224; idx += 512) ((unsigned*)hbuf)[idx] = 0;
    __syncthreads();

    // uniform (SGPR) row bases + one 32-bit per-lane offset
    const float* xpr[4];
    float* sqr[4];
#pragma unroll
    for (int r = 0; r < 4; r++) {
        xpr[r] = xp + (size_t)(m0 + r) * TT * N3;
        sqr[r] = seq_out ? seq_out + (size_t)(m0 + r) * TT * UU : nullptr;
    }
    unsigned voff = (unsigned)(q * 4 * TT) * N3 + (unsigned)(w * 32 + c);
    unsigned soff = (unsigned)(q * 4 * TT) * UU + (unsigned)(w * 32 + c);
    const unsigned dg[6] = {0u, 256u, 512u, 16u, 272u, 528u};  // nt col deltas

    // preload xp(t=0)
    float xv[6][4];
#pragma unroll
    for (int nt = 0; nt < 6; nt++)
#pragma unroll
        for (int r = 0; r < 4; r++) xv[nt][r] = xpr[r][voff + dg[nt]];

    for (int t = 0; t < TT; t++) {
        // acc init: z/r accs start at xp (b_rec folded in bias); hh at b_rec3
        f32x4 acc[6];
        float xh[2][4];
#pragma unroll
        for (int i = 0; i < 2; i++)
#pragma unroll
            for (int r = 0; r < 4; r++) {
                acc[3 * i + 0][r] = xv[3 * i + 0][r];
                acc[3 * i + 1][r] = xv[3 * i + 1][r];
                acc[3 * i + 2][r] = br3[i];
                xh[i][r] = xv[3 * i + 2][r];
            }

        // prefetch xp(t+1) (in flight under the MFMA loop)
        unsigned voff_n = (t + 1 < TT) ? voff + N3 : voff;
#pragma unroll
        for (int nt = 0; nt < 6; nt++)
#pragma unroll
            for (int r = 0; r < 4; r++) xv[nt][r] = xpr[r][voff_n + dg[nt]];
        voff = voff_n;

        // MFMA K-loop: A from LDS (m = c, k = kt*32 + q*8 + j), B from regs
        const f16* hb = &hbuf[t & 1][c][0];
#pragma unroll
        for (int kt = 0; kt < 8; kt++) {
            f16x8 a = *(const f16x8*)(hb + kt * 32 + q * 8);
#pragma unroll
            for (int nt = 0; nt < 6; nt++)
                acc[nt] = __builtin_amdgcn_mfma_f32_16x16x32_f16(a, uf[nt][kt], acc[nt], 0, 0, 0);
        }

        // gates: fully in-lane (z,r,hh co-located). D row = q*4+reg, col = c.
#pragma unroll
        for (int i = 0; i < 2; i++)
#pragma unroll
            for (int r = 0; r < 4; r++) {
                float z  = 1.f / (1.f + __expf(-acc[3 * i + 0][r]));
                float rr = 1.f / (1.f + __expf(-acc[3 * i + 1][r]));
                float hh = xh[i][r] + rr * acc[3 * i + 2][r];
                hh = hh > 0.f ? hh : 0.f;
                float hn = z * h_old[i][r] + (1.f - z) * hh;
                h_old[i][r] = hn;
                float hp = __shfl_xor(hn, 1);
                if (!(c & 1)) {
                    union { f16 h[2]; unsigned u32; } pk;
                    pk.h[0] = (f16)hn; pk.h[1] = (f16)hp;
                    *(unsigned*)&hbuf[(t + 1) & 1][q * 4 + r][w * 32 + i * 16 + c] = pk.u32;
                }
                if (seq_out) sqr[r][soff + i * 16] = hn;
            }
        soff += UU;
        __syncthreads();   // h(t+1) visible; also guards buffer reuse
    }

#pragma unroll
    for (int i = 0; i < 2; i++)
#pragma unroll
        for (int r = 0; r < 4; r++) {
            int b = m0 + q * 4 + r, u = w * 32 + i * 16 + c;
            state_out[b * UU + u] = h_old[i][r];
            if (extra_out) extra_out[b * UU + u] = h_old[i][r];
        }
}

extern "C" void kernel_launch(void* const* d_in, const int* in_sizes, int n_in,
                              void* d_out, int out_size, void* d_ws, size_t ws_size,
                              hipStream_t stream) {
    const float* x  = (const float*)d_in[0];
    const float* W1 = (const float*)d_in[1];
    const float* U1 = (const float*)d_in[2];
    const float* b1 = (const float*)d_in[3];
    const float* W2 = (const float*)d_in[4];
    const float* U2 = (const float*)d_in[5];
    const float* b2 = (const float*)d_in[6];
    float* out = (float*)d_out;

    f16x8* Up1; hipGetSymbolAddress((void**)&Up1, HIP_SYMBOL(g_Up1));
    f16x8* Up2; hipGetSymbolAddress((void**)&Up2, HIP_SYMBOL(g_Up2));
    float* seq1; hipGetSymbolAddress((void**)&seq1, HIP_SYMBOL(g_seq1));
    float* xp;   hipGetSymbolAddress((void**)&xp,   HIP_SYMBOL(g_xp));
    float* bi1;  hipGetSymbolAddress((void**)&bi1,  HIP_SYMBOL(g_bias1));
    float* bi2;  hipGetSymbolAddress((void**)&bi2,  HIP_SYMBOL(g_bias2));

    prep_upack<<<96, 256, 0, stream>>>(U1, Up1);   // 48*512 frags
    prep_upack<<<96, 256, 0, stream>>>(U2, Up2);
    prep_bias<<<3, 256, 0, stream>>>(b1, bi1);
    prep_bias<<<3, 256, 0, stream>>>(b2, bi2);

    // layer 1
    gemm_k15<<<dim3(BB * TT / 8, 3), 256, 0, stream>>>(x, W1, bi1, xp);
    gru_mfma<<<4, 512, 0, stream>>>(Up1, b1 + N3, xp, seq1, out + BB * UU, nullptr);

    // layer 2
    gemm_xp<<<dim3(BB * TT / 64, N3 / 64), 256, 0, stream>>>(seq1, W2, bi2, xp);
    gru_mfma<<<4, 512, 0, stream>>>(Up2, b2 + N3, xp, nullptr, out + 2 * BB * UU, out);
}

// Round 7
// 16219.725 us; speedup vs baseline: 1.1096x; 1.1096x over previous
//
#include <hip/hip_runtime.h>

#define TT 2048
#define UU 256
#define N3 768

typedef _Float16 f16;
typedef __attribute__((ext_vector_type(8))) _Float16 f16x8;   // 4 VGPRs
typedef __attribute__((ext_vector_type(4))) float     f32x4;

// Exchange buffers: [slot][rg][row][unit] f16 (64 KB each)
__device__ f16 g_h1[2][4][16][UU];
__device__ f16 g_h2[2][4][16][UU];
// B-operand fragments: frag f = usug*24 + gate*8 + kt  (usug = ug*2+us)
__device__ f16x8 g_U1p[384 * 64];
__device__ f16x8 g_U2p[384 * 64];
__device__ f16x8 g_W2p[384 * 64];
__device__ f16x8 g_W1p[48 * 64];     // K=32 (features 15..31 zero)
__device__ f16 g_xh[(size_t)64 * TT * 32];   // x padded to 32 features, f16

union AF { unsigned u[4]; f16x8 v; };

__device__ __forceinline__ void spinwait(int* f, int target, long& budget) {
    while (budget > 0) {
        int v = __hip_atomic_load(f, __ATOMIC_ACQUIRE, __HIP_MEMORY_SCOPE_AGENT);
        if (v >= target) return;
        budget--;
    }
}

__device__ __forceinline__ f16x8 load_af(const unsigned* base, unsigned idx) {
    AF a;
#pragma unroll
    for (int i = 0; i < 4; i++)
        a.u[i] = __hip_atomic_load((unsigned*)(base + idx + i),
                                   __ATOMIC_RELAXED, __HIP_MEMORY_SCOPE_AGENT);
    return a.v;
}

// ---- pack U1/U2/W2 (fp32 [256][768]) into B fragments ----------------------
__global__ __launch_bounds__(256) void pack_w256(const float* __restrict__ M,
                                                 f16x8* __restrict__ out) {
    int idx = blockIdx.x * 256 + threadIdx.x;   // [0, 384*64)
    int f = idx >> 6, lane = idx & 63;
    int usug = f / 24, g = (f % 24) >> 3, kt = f & 7;
    int q = lane >> 4, c = lane & 15;
    int col = g * 256 + (usug >> 1) * 32 + (usug & 1) * 16 + c;
    f16x8 v;
#pragma unroll
    for (int j = 0; j < 8; j++) v[j] = (f16)M[(kt * 32 + q * 8 + j) * N3 + col];
    out[idx] = v;
}

// ---- pack W1 (fp32 [15][768]) into K=32 zero-padded B fragments ------------
__global__ __launch_bounds__(256) void pack_w1(const float* __restrict__ M,
                                               f16x8* __restrict__ out) {
    int idx = blockIdx.x * 256 + threadIdx.x;   // [0, 48*64)
    int f = idx >> 6, lane = idx & 63;
    int usug = f / 3, g = f % 3;
    int q = lane >> 4, c = lane & 15;
    int col = g * 256 + (usug >> 1) * 32 + (usug & 1) * 16 + c;
    f16x8 v;
#pragma unroll
    for (int j = 0; j < 8; j++) {
        int k = q * 8 + j;
        v[j] = (k < 15) ? (f16)M[k * N3 + col] : (f16)0.f;
    }
    out[idx] = v;
}

// ---- pack x (fp32 [64][2048][15]) -> f16 [64][2048][32] --------------------
__global__ __launch_bounds__(256) void pack_x(const float* __restrict__ x,
                                              f16* __restrict__ xh) {
    int i = blockIdx.x * 256 + threadIdx.x;     // [0, 64*2048)
    const float* s = x + (size_t)i * 15;
    f16 tmp[32];
#pragma unroll
    for (int k = 0; k < 15; k++) tmp[k] = (f16)s[k];
#pragma unroll
    for (int k = 15; k < 32; k++) tmp[k] = (f16)0.f;
    f16x8* d = (f16x8*)(xh + (size_t)i * 32);
#pragma unroll
    for (int m = 0; m < 4; m++) d[m] = *(f16x8*)&tmp[m * 8];
}

// ---- fused 2-layer GRU recurrence --------------------------------------------
// 64 WGs x 256 thr. WG 0..31: layer1 (4 rg x 8 ug); 32..63: layer2.
// WG owns 16 batch rows x 32 units. Waves: us = w&1 (unit half), kq = w>>1
// (K half). h exchanged via agent-scope atomics; flags in d_ws (poisoned
// negative every launch; sentinels t+1 are monotonic -> replay-safe).
__global__ __launch_bounds__(256, 1) void gru_fused(
    const float* __restrict__ b1, const float* __restrict__ b2,
    float* __restrict__ out, int* __restrict__ flags)
{
    const int wg = blockIdx.x;
    const int layer = wg >> 5;
    const int id = wg & 31;
    const int rg = id >> 3, ug = id & 7;
    const int tid = threadIdx.x;
    const int w = tid >> 6, lane = tid & 63, q = lane >> 4, c = lane & 15;
    const int us = w & 1, kq = w >> 1;
    const int usug = ug * 2 + us;

    __shared__ float lred[2 * 64 * 17];   // k-reduce buffer, stride 17 (conflict-free)

    // B fragments -> registers, pinned
    const f16x8* Ub = layer ? g_U2p : g_U1p;
    f16x8 uf[3][4];
#pragma unroll
    for (int g = 0; g < 3; g++)
#pragma unroll
        for (int kt = 0; kt < 4; kt++) {
            uf[g][kt] = Ub[(usug * 24 + g * 8 + kq * 4 + kt) * 64 + lane];
            asm volatile("" : "+v"(uf[g][kt]));
        }
    f16x8 wf[3][4];
    if (layer) {
#pragma unroll
        for (int g = 0; g < 3; g++)
#pragma unroll
            for (int kt = 0; kt < 4; kt++) {
                wf[g][kt] = g_W2p[(usug * 24 + g * 8 + kq * 4 + kt) * 64 + lane];
                asm volatile("" : "+v"(wf[g][kt]));
            }
    } else if (kq == 0) {
#pragma unroll
        for (int g = 0; g < 3; g++) {
            wf[g][0] = g_W1p[(usug * 3 + g) * 64 + lane];
            asm volatile("" : "+v"(wf[g][0]));
        }
    }

    const int u = ug * 32 + us * 16 + c;   // this lane's gate unit
    const float* bb = layer ? b2 : b1;
    const float bz  = bb[u] + bb[N3 + u];
    const float brr = bb[256 + u] + bb[N3 + 256 + u];
    const float bhx = bb[512 + u];
    const float bhr = bb[N3 + 512 + u];

    float h_old[4] = {0.f, 0.f, 0.f, 0.f};

    int* l1f = flags + rg * 8;            // layer-1 flags of this rg
    int* l2f = flags + 32 + rg * 8;
    int* myflag = flags + layer * 32 + rg * 8 + ug;
    long budget = 200000000;

    const unsigned* h1w = (const unsigned*)g_h1;
    const unsigned* h2w = (const unsigned*)g_h2;
    unsigned* hw_out = (unsigned*)(layer ? g_h2 : g_h1);

    for (int t = 0; t < TT; t++) {
        // ---- spin phase: data-ready + overwrite guards
        if (tid < 16) {
            if (layer == 0) {
                if (tid < 8 && t >= 1) spinwait(l1f + tid, t, budget);        // h1(t)
                if (tid >= 8 && t >= 2) spinwait(l2f + (tid - 8), t - 1, budget); // L2 consumed h1(t-1)
            } else {
                if (tid < 8) spinwait(l1f + tid, t + 1, budget);              // h1(t+1) = seq1[t]
                if (tid >= 8 && t >= 1) spinwait(l2f + (tid - 8), t, budget); // h2(t) + overwrite guard
            }
        }
        __syncthreads();

        // ---- acc init (bias only in kq0; kq1 partials start at 0)
        f32x4 az, ar, ahr, ahx;
        if (kq == 0) {
            az = f32x4{bz, bz, bz, bz};   ar  = f32x4{brr, brr, brr, brr};
            ahr = f32x4{bhr, bhr, bhr, bhr}; ahx = f32x4{bhx, bhx, bhx, bhx};
        } else {
            az = f32x4{0,0,0,0}; ar = az; ahr = az; ahx = az;
        }

        if (layer == 0) {
            if (kq == 0) {   // x @ W1 (K=32 padded)
                f16x8 ax = *(const f16x8*)(g_xh + ((size_t)(rg * 16 + c) * TT + t) * 32 + q * 8);
                az  = __builtin_amdgcn_mfma_f32_16x16x32_f16(ax, wf[0][0], az, 0, 0, 0);
                ar  = __builtin_amdgcn_mfma_f32_16x16x32_f16(ax, wf[1][0], ar, 0, 0, 0);
                ahx = __builtin_amdgcn_mfma_f32_16x16x32_f16(ax, wf[2][0], ahx, 0, 0, 0);
            }
            if (t > 0) {     // h1(t) @ U1
                unsigned abase = (((unsigned)(t & 1) * 4 + rg) * 16 + c) * 128;
                f16x8 ah[4];
#pragma unroll
                for (int kt = 0; kt < 4; kt++)
                    ah[kt] = load_af(h1w, abase + (kq * 4 + kt) * 16 + q * 4);
#pragma unroll
                for (int kt = 0; kt < 4; kt++) {
                    az  = __builtin_amdgcn_mfma_f32_16x16x32_f16(ah[kt], uf[0][kt], az, 0, 0, 0);
                    ar  = __builtin_amdgcn_mfma_f32_16x16x32_f16(ah[kt], uf[1][kt], ar, 0, 0, 0);
                    ahr = __builtin_amdgcn_mfma_f32_16x16x32_f16(ah[kt], uf[2][kt], ahr, 0, 0, 0);
                }
            }
        } else {
            // xp2 = h1(t+1) @ W2
            unsigned xbase = (((unsigned)((t + 1) & 1) * 4 + rg) * 16 + c) * 128;
            f16x8 axp[4];
#pragma unroll
            for (int kt = 0; kt < 4; kt++)
                axp[kt] = load_af(h1w, xbase + (kq * 4 + kt) * 16 + q * 4);
            if (t > 0) {     // h2(t) @ U2
                unsigned rbase = (((unsigned)(t & 1) * 4 + rg) * 16 + c) * 128;
                f16x8 ah[4];
#pragma unroll
                for (int kt = 0; kt < 4; kt++)
                    ah[kt] = load_af(h2w, rbase + (kq * 4 + kt) * 16 + q * 4);
#pragma unroll
                for (int kt = 0; kt < 4; kt++) {
                    az  = __builtin_amdgcn_mfma_f32_16x16x32_f16(ah[kt], uf[0][kt], az, 0, 0, 0);
                    ar  = __builtin_amdgcn_mfma_f32_16x16x32_f16(ah[kt], uf[1][kt], ar, 0, 0, 0);
                    ahr = __builtin_amdgcn_mfma_f32_16x16x32_f16(ah[kt], uf[2][kt], ahr, 0, 0, 0);
                }
            }
#pragma unroll
            for (int kt = 0; kt < 4; kt++) {
                az  = __builtin_amdgcn_mfma_f32_16x16x32_f16(axp[kt], wf[0][kt], az, 0, 0, 0);
                ar  = __builtin_amdgcn_mfma_f32_16x16x32_f16(axp[kt], wf[1][kt], ar, 0, 0, 0);
                ahx = __builtin_amdgcn_mfma_f32_16x16x32_f16(axp[kt], wf[2][kt], ahx, 0, 0, 0);
            }
        }

        // ---- K-reduce across kq pair
        if (kq == 1) {
            int base = (us * 64 + lane) * 17;
#pragma unroll
            for (int i = 0; i < 4; i++) {
                lred[base + i]      = az[i];
                lred[base + 4 + i]  = ar[i];
                lred[base + 8 + i]  = ahr[i];
                lred[base + 12 + i] = ahx[i];
            }
        }
        __syncthreads();

        if (kq == 0) {
            int base = (us * 64 + lane) * 17;
            float hn4[4];
#pragma unroll
            for (int r = 0; r < 4; r++) {
                float zp = az[r]  + lred[base + r];
                float rp = ar[r]  + lred[base + 4 + r];
                float hr = ahr[r] + lred[base + 8 + r];
                float hx = ahx[r] + lred[base + 12 + r];
                float z  = 1.f / (1.f + __expf(-zp));
                float rr = 1.f / (1.f + __expf(-rp));
                float hh = hx + rr * hr;
                hh = hh > 0.f ? hh : 0.f;
                float hn = z * h_old[r] + (1.f - z) * hh;
                h_old[r] = hn;
                hn4[r] = hn;
            }
            // publish h(t+1) into slot (t+1)&1 (f16 pairs, agent-scope)
            unsigned rowb = ((unsigned)((t + 1) & 1) * 4 + rg) * 16;
#pragma unroll
            for (int r = 0; r < 4; r++) {
                float hp = __shfl_xor(hn4[r], 1);
                if (!(c & 1)) {
                    union { f16 h[2]; unsigned w32; } pk;
                    pk.h[0] = (f16)hn4[r]; pk.h[1] = (f16)hp;
                    unsigned idx = (rowb + q * 4 + r) * 128 + (u >> 1);
                    __hip_atomic_store(hw_out + idx, pk.w32,
                                       __ATOMIC_RELAXED, __HIP_MEMORY_SCOPE_AGENT);
                }
            }
            __builtin_amdgcn_s_waitcnt(0);   // own stores at coherence point
        }
        __syncthreads();
        if (tid == 0)
            __hip_atomic_store(myflag, t + 1, __ATOMIC_RELEASE, __HIP_MEMORY_SCOPE_AGENT);
    }

    // ---- final states: h(2048)
    if (kq == 0) {
#pragma unroll
        for (int r = 0; r < 4; r++) {
            int b = rg * 16 + q * 4 + r;
            if (layer == 0) {
                out[16384 + b * UU + u] = h_old[r];              // state1
            } else {
                out[b * UU + u] = h_old[r];                      // x (= seq2 last)
                out[32768 + b * UU + u] = h_old[r];              // state2
            }
        }
    }
}

extern "C" void kernel_launch(void* const* d_in, const int* in_sizes, int n_in,
                              void* d_out, int out_size, void* d_ws, size_t ws_size,
                              hipStream_t stream) {
    const float* x  = (const float*)d_in[0];
    const float* W1 = (const float*)d_in[1];
    const float* U1 = (const float*)d_in[2];
    const float* b1 = (const float*)d_in[3];
    const float* W2 = (const float*)d_in[4];
    const float* U2 = (const float*)d_in[5];
    const float* b2 = (const float*)d_in[6];
    float* out = (float*)d_out;

    f16x8* U1p; hipGetSymbolAddress((void**)&U1p, HIP_SYMBOL(g_U1p));
    f16x8* U2p; hipGetSymbolAddress((void**)&U2p, HIP_SYMBOL(g_U2p));
    f16x8* W2p; hipGetSymbolAddress((void**)&W2p, HIP_SYMBOL(g_W2p));
    f16x8* W1p; hipGetSymbolAddress((void**)&W1p, HIP_SYMBOL(g_W1p));
    f16*   xh;  hipGetSymbolAddress((void**)&xh,  HIP_SYMBOL(g_xh));

    pack_w256<<<96, 256, 0, stream>>>(U1, U1p);
    pack_w256<<<96, 256, 0, stream>>>(U2, U2p);
    pack_w256<<<96, 256, 0, stream>>>(W2, W2p);
    pack_w1<<<12, 256, 0, stream>>>(W1, W1p);
    pack_x<<<512, 256, 0, stream>>>(x, xh);

    gru_fused<<<64, 256, 0, stream>>>(b1, b2, out, (int*)d_ws);
}